// Round 16
// baseline (216.465 us; speedup 1.0000x reference)
//
#include <hip/hip_runtime.h>
#include <hip/hip_fp16.h>

#define N_NODES 100000
#define N_EDGES 800000
#define FDIM 64
#define TILE_ROWS 32
#define N_TILES (N_NODES / TILE_ROWS)        // 3125 exactly
#define SCAN_BLOCK 1024
#define N_SCAN_BLOCKS ((N_NODES + SCAN_BLOCK - 1) / SCAN_BLOCK)   // 98
#define ROWS_PER_XCD (N_NODES / 8)           // 12500 exactly
#define HIST_SLICES 16
#define EDGES_PER_SLICE (N_EDGES / HIST_SLICES)   // 50000 exactly

typedef int   iv4 __attribute__((ext_vector_type(4)));
typedef float fv4 __attribute__((ext_vector_type(4)));

// ---------------------------------------------------------------------------
// Kernel 1: xw(fp16) = x @ w — PURE projection. R15 post-mortem: the fused
// histogram's 800K random cross-XCD atomics were bouncing count[] lines
// between L2s (gemm WRITE 37.4MB vs 13.2 expected) and ran concurrently with
// x staging -> gemm at 2.2x its compute floor. Hist moved to its own
// XCD-partitioned LDS kernel.
// ---------------------------------------------------------------------------
__global__ __launch_bounds__(256) void gemm_kernel(
    const float* __restrict__ x, const float* __restrict__ w,
    __half* __restrict__ xwh) {
    const int tid = threadIdx.x;
    const int bid = blockIdx.x;

    __shared__ float wq[16 * 64 * 4];        // [k0][f][j] = w[4k0+j][f], 16KB
    __shared__ float xs[TILE_ROWS * FDIM];   // 8KB x tile

    const int lane = tid & 63;
    const int wid = tid >> 6;                // wave 0..3

    // stage W transposed: wave w handles k0 = w*4..w*4+3
    float4* wq4 = reinterpret_cast<float4*>(wq);
    #pragma unroll
    for (int it = 0; it < 4; ++it) {
        const int k0 = wid * 4 + it;
        float4 wv;
        wv.x = w[(4 * k0 + 0) * FDIM + lane];   // coalesced 256B per load
        wv.y = w[(4 * k0 + 1) * FDIM + lane];
        wv.z = w[(4 * k0 + 2) * FDIM + lane];
        wv.w = w[(4 * k0 + 3) * FDIM + lane];
        wq4[k0 * 64 + lane] = wv;               // contiguous 1KB wave write
    }

    // stage x tile: 512 float4, 2 per thread
    {
        const float4* xg4 = reinterpret_cast<const float4*>(
            x + (size_t)bid * TILE_ROWS * FDIM);
        float4* xs4 = reinterpret_cast<float4*>(xs);
        xs4[tid] = xg4[tid];
        xs4[256 + tid] = xg4[256 + tid];
    }
    __syncthreads();

    // wave w computes rows w*8..w*8+7 of the tile; lane = feature
    const float4* xs4 = reinterpret_cast<const float4*>(xs);
    const int rbase = wid * 8;
    float acc[8] = {0.f, 0.f, 0.f, 0.f, 0.f, 0.f, 0.f, 0.f};
    #pragma unroll 4
    for (int k0 = 0; k0 < 16; ++k0) {
        const float4 wv = wq4[k0 * 64 + lane];   // contiguous read
        #pragma unroll
        for (int rr = 0; rr < 8; ++rr) {
            const float4 xv = xs4[(rbase + rr) * 16 + k0];  // LDS broadcast
            acc[rr] += xv.x * wv.x + xv.y * wv.y + xv.z * wv.z + xv.w * wv.w;
        }
    }

    const int growbase = bid * TILE_ROWS + rbase;
    #pragma unroll
    for (int rr = 0; rr < 8; ++rr)
        xwh[(size_t)(growbase + rr) * FDIM + lane] = __float2half(acc[rr]);
}

// ---------------------------------------------------------------------------
// Kernel 2: XCD-partitioned LDS histogram. 128 blocks = 16 edge-slices x 8
// XCDs. Block b (xcd=b&7) owns contiguous rows [xcd*12500,(xcd+1)*12500):
// builds a 50KB LDS histogram of its slice's edges in-range, then flushes
// with coalesced atomics — all writers of a count line are on ONE XCD.
// Replaces 800K random cross-XCD global atomics (the R15 line-bounce).
// ---------------------------------------------------------------------------
__global__ __launch_bounds__(256) void hist_lds_kernel(
    const int* __restrict__ erow, int* __restrict__ count) {
    const int xcd = blockIdx.x & 7;          // XCD this block lands on (m09)
    const int slice = blockIdx.x >> 3;       // 0..15
    const int lo = xcd * ROWS_PER_XCD;
    __shared__ int lhist[ROWS_PER_XCD];      // 50000 B
    for (int i = threadIdx.x; i < ROWS_PER_XCD; i += 256) lhist[i] = 0;
    __syncthreads();

    const int sbeg = slice * EDGES_PER_SLICE;
    const int send = sbeg + EDGES_PER_SLICE;
    for (int e0 = sbeg + threadIdx.x * 4; e0 < send; e0 += 1024) {
        iv4 r = __builtin_nontemporal_load(
            reinterpret_cast<const iv4*>(erow + e0));
        #pragma unroll
        for (int j = 0; j < 4; ++j) {
            const int rel = r[j] - lo;
            if ((unsigned)rel < (unsigned)ROWS_PER_XCD)
                atomicAdd(&lhist[rel], 1);   // LDS atomic
        }
    }
    __syncthreads();

    for (int i = threadIdx.x; i < ROWS_PER_XCD; i += 256) {
        const int v = lhist[i];
        if (v) atomicAdd(&count[lo + i], v); // XCD-local global atomic
    }
}

// ---------------------------------------------------------------------------
// Kernel 3: per-1024-block scan -> block-local exclusive starts + block sums
// ---------------------------------------------------------------------------
__global__ __launch_bounds__(SCAN_BLOCK) void scan_block_kernel(
    const int* __restrict__ count, int* __restrict__ starts,
    int* __restrict__ blockSums) {
    __shared__ int tmp[SCAN_BLOCK];
    const int tid = threadIdx.x;
    const int i = blockIdx.x * SCAN_BLOCK + tid;
    const int v = (i < N_NODES) ? count[i] : 0;
    tmp[tid] = v;
    __syncthreads();
    for (int off = 1; off < SCAN_BLOCK; off <<= 1) {
        int t = (tid >= off) ? tmp[tid - off] : 0;
        __syncthreads();
        tmp[tid] += t;
        __syncthreads();
    }
    if (i < N_NODES) starts[i] = tmp[tid] - v;
    if (tid == SCAN_BLOCK - 1) blockSums[blockIdx.x] = tmp[tid];
}

// ---------------------------------------------------------------------------
// Kernel 4: redundant block-sum scan in LDS + offset add + sentinel.
// ---------------------------------------------------------------------------
__global__ __launch_bounds__(256) void scanadd_kernel(
    int* __restrict__ starts, const int* __restrict__ blockSums,
    int* __restrict__ cursor) {
    __shared__ int ssum[128];
    const int tid = threadIdx.x;
    if (tid < 128) ssum[tid] = (tid < N_SCAN_BLOCKS) ? blockSums[tid] : 0;
    __syncthreads();
    for (int off = 1; off < 128; off <<= 1) {
        int t = (tid < 128 && tid >= off) ? ssum[tid - off] : 0;
        __syncthreads();
        if (tid < 128) ssum[tid] += t;   // inclusive
        __syncthreads();
    }
    const int i = blockIdx.x * 256 + tid;
    if (i < N_NODES) {
        const int j = i >> 10;
        const int add = (j == 0) ? 0 : ssum[j - 1];
        const int s = starts[i] + add;
        starts[i] = s;
        cursor[i] = s;
    } else if (i == N_NODES) {
        starts[N_NODES] = N_EDGES;
    }
}

// ---------------------------------------------------------------------------
// Kernel 5: RANGE-partitioned bucket fill (unchanged — fell below top-5 in
// R15 after the contiguous-range fix).
// ---------------------------------------------------------------------------
__global__ __launch_bounds__(256) void fill_xcd_kernel(
    const int* __restrict__ erow, const int* __restrict__ ecol,
    const float* __restrict__ ew, int* __restrict__ cursor,
    uint2* __restrict__ recs) {
    const int xcd = blockIdx.x & 7;
    const int lo = xcd * ROWS_PER_XCD;
    const int hi = lo + ROWS_PER_XCD;
    const int chunk = blockIdx.x >> 3;
    const int base = (chunk * 256 + threadIdx.x) * 4;
    if (base + 3 < N_EDGES) {
        iv4 r = __builtin_nontemporal_load(
            reinterpret_cast<const iv4*>(erow + base));
        iv4 c = __builtin_nontemporal_load(
            reinterpret_cast<const iv4*>(ecol + base));
        fv4 wt = __builtin_nontemporal_load(
            reinterpret_cast<const fv4*>(ew + base));
        #pragma unroll
        for (int j = 0; j < 4; ++j) {
            const int rr = r[j];
            if (rr >= lo && rr < hi) {
                const int p = atomicAdd(&cursor[rr], 1);
                recs[p] = make_uint2((unsigned)c[j], __float_as_uint(wt[j]));
            }
        }
    } else {
        for (int e = base; e < N_EDGES; ++e) {
            const int rr = erow[e];
            if (rr >= lo && rr < hi) {
                const int p = atomicAdd(&cursor[rr], 1);
                recs[p] = make_uint2((unsigned)ecol[e], __float_as_uint(ew[e]));
            }
        }
    }
}

// ---------------------------------------------------------------------------
// Kernel 6: aggregate from fp16 xw. (UNCHANGED; below top-5 cutoff since R10.)
// ---------------------------------------------------------------------------
__global__ __launch_bounds__(256) void aggregate_h_kernel(
    const __half* __restrict__ xwh, const uint2* __restrict__ recs,
    const int* __restrict__ starts, const float* __restrict__ b,
    float* __restrict__ out) {
    const int lane = threadIdx.x & 63;
    const int g = lane >> 4;        // row slot within wave
    const int s = lane & 15;        // feature quad
    const int wave = (int)((blockIdx.x * blockDim.x + threadIdx.x) >> 6);
    const int nwaves = (int)((gridDim.x * (size_t)blockDim.x) >> 6);
    const float4 bias = reinterpret_cast<const float4*>(b)[s];
    const unsigned long long* recs8 =
        reinterpret_cast<const unsigned long long*>(recs);

    for (int r0 = wave * 4; r0 < N_NODES; r0 += nwaves * 4) {
        const int r = r0 + g;
        if (r < N_NODES) {
            const int st = starts[r];
            const int cnt = starts[r + 1] - st;
            float4 acc = bias;
            int k = 0;
            for (; k + 4 <= cnt; k += 4) {
                unsigned long long p0 = __builtin_nontemporal_load(recs8 + st + k + 0);
                unsigned long long p1 = __builtin_nontemporal_load(recs8 + st + k + 1);
                unsigned long long p2 = __builtin_nontemporal_load(recs8 + st + k + 2);
                unsigned long long p3 = __builtin_nontemporal_load(recs8 + st + k + 3);
                uint2 g0 = *reinterpret_cast<const uint2*>(
                    xwh + (size_t)(unsigned)p0 * FDIM + 4 * s);
                uint2 g1 = *reinterpret_cast<const uint2*>(
                    xwh + (size_t)(unsigned)p1 * FDIM + 4 * s);
                uint2 g2 = *reinterpret_cast<const uint2*>(
                    xwh + (size_t)(unsigned)p2 * FDIM + 4 * s);
                uint2 g3 = *reinterpret_cast<const uint2*>(
                    xwh + (size_t)(unsigned)p3 * FDIM + 4 * s);
                const float w0 = __uint_as_float((unsigned)(p0 >> 32));
                const float w1 = __uint_as_float((unsigned)(p1 >> 32));
                const float w2 = __uint_as_float((unsigned)(p2 >> 32));
                const float w3 = __uint_as_float((unsigned)(p3 >> 32));
                float2 a0 = __half22float2(*reinterpret_cast<__half2*>(&g0.x));
                float2 b0 = __half22float2(*reinterpret_cast<__half2*>(&g0.y));
                float2 a1 = __half22float2(*reinterpret_cast<__half2*>(&g1.x));
                float2 b1 = __half22float2(*reinterpret_cast<__half2*>(&g1.y));
                float2 a2 = __half22float2(*reinterpret_cast<__half2*>(&g2.x));
                float2 b2 = __half22float2(*reinterpret_cast<__half2*>(&g2.y));
                float2 a3 = __half22float2(*reinterpret_cast<__half2*>(&g3.x));
                float2 b3 = __half22float2(*reinterpret_cast<__half2*>(&g3.y));
                acc.x += a0.x * w0 + a1.x * w1 + a2.x * w2 + a3.x * w3;
                acc.y += a0.y * w0 + a1.y * w1 + a2.y * w2 + a3.y * w3;
                acc.z += b0.x * w0 + b1.x * w1 + b2.x * w2 + b3.x * w3;
                acc.w += b0.y * w0 + b1.y * w1 + b2.y * w2 + b3.y * w3;
            }
            for (; k < cnt; ++k) {
                unsigned long long p0 = __builtin_nontemporal_load(recs8 + st + k);
                uint2 g0 = *reinterpret_cast<const uint2*>(
                    xwh + (size_t)(unsigned)p0 * FDIM + 4 * s);
                const float w0 = __uint_as_float((unsigned)(p0 >> 32));
                float2 a0 = __half22float2(*reinterpret_cast<__half2*>(&g0.x));
                float2 b0 = __half22float2(*reinterpret_cast<__half2*>(&g0.y));
                acc.x += a0.x * w0; acc.y += a0.y * w0;
                acc.z += b0.x * w0; acc.w += b0.y * w0;
            }
            reinterpret_cast<float4*>(out + (size_t)r * FDIM)[s] = acc;
        }
    }
}

// --------------------------- atomic fallback (unused in practice) ----------
__global__ __launch_bounds__(256) void gemm_rm_kernel(
    const float* __restrict__ x, const float* __restrict__ w,
    float* __restrict__ xw) {
    const int lane = threadIdx.x & 63;
    float wr[FDIM];
    #pragma unroll
    for (int k = 0; k < FDIM; ++k) wr[k] = w[k * FDIM + lane];
    const int gwave = blockIdx.x * 4 + (threadIdx.x >> 6);
    const int nwaves = gridDim.x * 4;
    for (int row = gwave; row < N_NODES; row += nwaves) {
        const float4* xr = reinterpret_cast<const float4*>(x + (size_t)row * FDIM);
        float a0 = 0.f, a1 = 0.f, a2 = 0.f, a3 = 0.f;
        #pragma unroll
        for (int k0 = 0; k0 < FDIM / 4; ++k0) {
            float4 xv = xr[k0];
            a0 += xv.x * wr[4 * k0 + 0];
            a1 += xv.y * wr[4 * k0 + 1];
            a2 += xv.z * wr[4 * k0 + 2];
            a3 += xv.w * wr[4 * k0 + 3];
        }
        xw[(size_t)row * FDIM + lane] = (a0 + a1) + (a2 + a3);
    }
}

__global__ __launch_bounds__(256) void init_out_kernel(
    float* __restrict__ out, const float* __restrict__ b) {
    const float4* b4 = reinterpret_cast<const float4*>(b);
    float4* out4 = reinterpret_cast<float4*>(out);
    const size_t total = (size_t)N_NODES * FDIM / 4;
    size_t i = (size_t)blockIdx.x * blockDim.x + threadIdx.x;
    const size_t stride = (size_t)gridDim.x * blockDim.x;
    for (; i < total; i += stride) out4[i] = b4[i & 15];
}

__global__ __launch_bounds__(256) void scatter_kernel(
    const float* __restrict__ xw, const float* __restrict__ ew,
    const int* __restrict__ erow, const int* __restrict__ ecol,
    float* __restrict__ out) {
    const int lane = threadIdx.x & 63;
    const int g = lane >> 4;
    const int s = lane & 15;
    const int wave = (int)((blockIdx.x * blockDim.x + threadIdx.x) >> 6);
    const int nwaves = (int)((gridDim.x * (size_t)blockDim.x) >> 6);
    for (int e0 = wave * 4; e0 < N_EDGES; e0 += nwaves * 4) {
        const int e = e0 + g;
        if (e < N_EDGES) {
            const int c = ecol[e];
            const int r = erow[e];
            const float wgt = ew[e];
            const float4 v =
                reinterpret_cast<const float4*>(xw + (size_t)c * FDIM)[s];
            float* dst = out + (size_t)r * FDIM + 4 * s;
            atomicAdd(dst + 0, v.x * wgt);
            atomicAdd(dst + 1, v.y * wgt);
            atomicAdd(dst + 2, v.z * wgt);
            atomicAdd(dst + 3, v.w * wgt);
        }
    }
}

extern "C" void kernel_launch(void* const* d_in, const int* in_sizes, int n_in,
                              void* d_out, int out_size, void* d_ws, size_t ws_size,
                              hipStream_t stream) {
    const float* x  = (const float*)d_in[0];
    const float* w  = (const float*)d_in[1];
    const float* b  = (const float*)d_in[2];
    const float* ew = (const float*)d_in[3];
    const int* erow = (const int*)d_in[4];
    const int* ecol = (const int*)d_in[5];
    float* out = (float*)d_out;

    char* ws = (char*)d_ws;
    const size_t XWH_BYTES  = (size_t)N_NODES * FDIM * 2;      // 12.8 MB fp16
    const size_t REC_BYTES  = (size_t)N_EDGES * 8;             // 6.4 MB
    const size_t CNT_BYTES  = (size_t)N_NODES * 4;             // 0.4 MB
    const size_t ST_BYTES   = ((size_t)(N_NODES + 1) * 4 + 15) & ~(size_t)15;
    const size_t SUMS_BYTES = 512;
    const size_t NEED = XWH_BYTES + REC_BYTES + CNT_BYTES + ST_BYTES +
                        CNT_BYTES + SUMS_BYTES;                // ~20.9 MB

    if (ws_size >= NEED) {
        __half* xwh    = (__half*)ws;
        uint2* recs    = (uint2*)(ws + XWH_BYTES);
        int* count     = (int*)(ws + XWH_BYTES + REC_BYTES);
        int* starts    = (int*)(ws + XWH_BYTES + REC_BYTES + CNT_BYTES);
        int* cursor    = (int*)(ws + XWH_BYTES + REC_BYTES + CNT_BYTES + ST_BYTES);
        int* blockSums = (int*)(ws + XWH_BYTES + REC_BYTES + CNT_BYTES + ST_BYTES + CNT_BYTES);

        const int gE4 = (N_EDGES / 4 + 255) / 256;   // 782
        const int gN  = (N_NODES + 255) / 256 + 1;   // 392 (covers sentinel)

        hipMemsetAsync(count, 0, CNT_BYTES, stream);            // zero degrees
        gemm_kernel<<<N_TILES, 256, 0, stream>>>(x, w, xwh);
        hist_lds_kernel<<<HIST_SLICES * 8, 256, 0, stream>>>(erow, count);
        scan_block_kernel<<<N_SCAN_BLOCKS, SCAN_BLOCK, 0, stream>>>(count, starts, blockSums);
        scanadd_kernel<<<gN, 256, 0, stream>>>(starts, blockSums, cursor);
        fill_xcd_kernel<<<gE4 * 8, 256, 0, stream>>>(erow, ecol, ew, cursor, recs);
        aggregate_h_kernel<<<2048, 256, 0, stream>>>(xwh, recs, starts, b, out);
    } else {
        // fallback: f32 xw + atomic scatter (needs 25.6 MB)
        float* xw = (float*)ws;
        gemm_rm_kernel<<<2048, 256, 0, stream>>>(x, w, xw);
        init_out_kernel<<<2048, 256, 0, stream>>>(out, b);
        scatter_kernel<<<2048, 256, 0, stream>>>(xw, ew, erow, ecol, out);
    }
}